// Round 20
// baseline (256.499 us; speedup 1.0000x reference)
//
#include <hip/hip_runtime.h>

#define NN 128
#define DD 768
#define TT 16
#define PP 196
#define NSL 98                    // slices per b, 2 p each
#define NTILE (8 * NSL)           // 784
#define NWORK 512                 // persistent blocks = exact device capacity
#define SCL 0.03608439182435161f  // 1/sqrt(768)

typedef short short8 __attribute__((ext_vector_type(8)));
typedef float f32x4 __attribute__((ext_vector_type(4)));

static __device__ __forceinline__ ushort f2bf(float f) {
    union { float f; unsigned int u; } a; a.f = f;
    unsigned int r = a.u + 0x7fffu + ((a.u >> 16) & 1u);
    return (ushort)(r >> 16);
}
static __device__ __forceinline__ float bf2f(ushort u) {
    union { unsigned int u; float f; } c; c.u = (unsigned int)u << 16; return c.f;
}

// Verified (R4/R5/R13) swizzled LDS index for a 32x768 bf16 tile.
static __device__ __forceinline__ int vidx(int r, int d) {
    return r * DD + ((((d >> 3) ^ (r & 7)) << 3) | (d & 7));
}

// Raw workgroup barrier: drain LDS ops only (NOT vmcnt).
static __device__ __forceinline__ void bar_lgkm() {
    asm volatile("s_waitcnt lgkmcnt(0)" ::: "memory");
    __builtin_amdgcn_s_barrier();
    __builtin_amdgcn_sched_barrier(0);
}

// -------- K0: zero out + counters + LayerNorm of 128 cls rows --------
__global__ __launch_bounds__(256) void k_lnq(const float* __restrict__ x,
                                             const float* __restrict__ gamma,
                                             const float* __restrict__ beta,
                                             ushort* __restrict__ qn,
                                             float* __restrict__ out,
                                             int* __restrict__ cnt) {
    if (blockIdx.x == 0 && threadIdx.x < 2) cnt[threadIdx.x] = 0;
    int zi = blockIdx.x * 256 + threadIdx.x;   // 0..8191
    float4 z = {0.f, 0.f, 0.f, 0.f};
    ((float4*)out)[zi]         = z;
    ((float4*)out)[zi + 8192]  = z;
    ((float4*)out)[zi + 16384] = z;

    int row  = (blockIdx.x << 2) + (threadIdx.x >> 6);   // 0..127
    int lane = threadIdx.x & 63;
    const float4* xr = (const float4*)(x + (size_t)row * DD);
    float4 v[3];
    float s = 0.f, ss = 0.f;
#pragma unroll
    for (int j = 0; j < 3; ++j) {
        v[j] = xr[lane + 64 * j];
        s  += v[j].x + v[j].y + v[j].z + v[j].w;
        ss = fmaf(v[j].x, v[j].x, ss); ss = fmaf(v[j].y, v[j].y, ss);
        ss = fmaf(v[j].z, v[j].z, ss); ss = fmaf(v[j].w, v[j].w, ss);
    }
#pragma unroll
    for (int o = 32; o > 0; o >>= 1) { s += __shfl_xor(s, o); ss += __shfl_xor(ss, o); }
    float mu  = s * (1.f / DD);
    float var = fmaf(ss, 1.f / DD, -mu * mu);
    float rs  = rsqrtf(var + 1e-5f);
    const float4* g4 = (const float4*)gamma;
    const float4* b4 = (const float4*)beta;
    ushort4* outr = (ushort4*)(qn + (size_t)row * DD);
#pragma unroll
    for (int j = 0; j < 3; ++j) {
        int i4 = lane + 64 * j;
        float4 g = g4[i4], b = b4[i4];
        ushort4 o4;
        o4.x = f2bf((v[j].x - mu) * rs * g.x + b.x);
        o4.y = f2bf((v[j].y - mu) * rs * g.y + b.y);
        o4.z = f2bf((v[j].z - mu) * rs * g.z + b.z);
        o4.w = f2bf((v[j].w - mu) * rs * g.w + b.w);
        outr[i4] = o4;
    }
}

// ---- verbatim R13 tile body (USE_PART selects partial-store vs atomics) ----
template<bool USE_PART>
static __device__ __forceinline__ void tile_body(
    int gid, ushort* __restrict__ Vl, float* __restrict__ Sl,
    ushort* __restrict__ Wl, const float* __restrict__ x,
    const float* __restrict__ gamma, const float* __restrict__ beta,
    const ushort* __restrict__ qn, ushort* __restrict__ part,
    float* __restrict__ out) {
    int tid = threadIdx.x;
    int b = gid & 7, sl = gid >> 3;     // sl = 0..97
    int w = tid >> 6, l = tid & 63;
    int l15 = l & 15, lh = l >> 4;

    // ---- stage: thread = (row r = tid>>4, j = tid&15); LN fused, pack bf16 --
    {
        int r = tid >> 4, j = tid & 15;
        const float* vrow =
            x + ((size_t)(1 + sl * 2 + (r >> 4)) * NN + b * TT + (r & 15)) * DD;
        float4 c[12];
#pragma unroll
        for (int k = 0; k < 12; ++k) c[k] = *(const float4*)(vrow + (j + 16 * k) * 4);
        float s1 = 0.f, s2 = 0.f;
#pragma unroll
        for (int k = 0; k < 12; ++k) {
            float4 v = c[k];
            s1 += v.x + v.y + v.z + v.w;
            s2 = fmaf(v.x, v.x, s2); s2 = fmaf(v.y, v.y, s2);
            s2 = fmaf(v.z, v.z, s2); s2 = fmaf(v.w, v.w, s2);
        }
#pragma unroll
        for (int o = 1; o < 16; o <<= 1) { s1 += __shfl_xor(s1, o); s2 += __shfl_xor(s2, o); }
        float mu  = s1 * (1.f / DD);
        float var = fmaf(s2, 1.f / DD, -mu * mu);
        float rs  = rsqrtf(var + 1e-5f);
        const float4* g4 = (const float4*)gamma;
        const float4* b4 = (const float4*)beta;
#pragma unroll
        for (int k = 0; k < 12; ++k) {
            int c4 = j + 16 * k;
            float4 g = g4[c4], e = b4[c4];
            float4 v = c[k];
            ushort4 ut;
            ut.x = f2bf((v.x - mu) * rs * g.x + e.x);
            ut.y = f2bf((v.y - mu) * rs * g.y + e.y);
            ut.z = f2bf((v.z - mu) * rs * g.z + e.z);
            ut.w = f2bf((v.w - mu) * rs * g.w + e.w);
            *(ushort4*)&Vl[vidx(r, c4 * 4)] = ut;
        }
    }
    bar_lgkm();

    // ---- mm1: wave w covers K-slice [w*96, w*96+96), both 16-col groups ----
    {
        const ushort* qrow = qn + (size_t)(b * TT + l15) * DD + w * 96 + lh * 8;
        short8 qf[3];
#pragma unroll
        for (int s = 0; s < 3; ++s) qf[s] = *(const short8*)(qrow + s * 32);
#pragma unroll
        for (int cg = 0; cg < 2; ++cg) {
            f32x4 sacc = (f32x4){0.f, 0.f, 0.f, 0.f};
            int vr = cg * 16 + l15;
#pragma unroll
            for (int s = 0; s < 3; ++s) {
                int k0 = w * 96 + s * 32 + lh * 8;
                short8 bfr = *(const short8*)&Vl[vidx(vr, k0)];
                sacc = __builtin_amdgcn_mfma_f32_16x16x32_bf16(qf[s], bfr, sacc, 0, 0, 0);
            }
#pragma unroll
            for (int q = 0; q < 4; ++q)
                Sl[(w * TT + lh * 4 + q) * 33 + cg * 16 + l15] = sacc[q];
        }
    }
    bar_lgkm();

    // ---- W: 512 threads = (t, rr in 0..31): sum 8 K-slices, band sigmoid ----
    {
        int t  = tid >> 5, rr = tid & 31;
        float s = 0.f;
#pragma unroll
        for (int k = 0; k < 8; ++k) s += Sl[(k * TT + t) * 33 + rr];
        int m = rr & 15;
        int dlt = m - t;
        float wv = (dlt <= 2 && dlt >= -2)
                     ? (1.f / (1.f + __expf(-s * SCL)) - 0.5f) : 0.f;
        Wl[t * 32 + rr] = f2bf(wv);
    }
    bar_lgkm();

    // ---- mm2: K=32 (all real rows), wave owns d-slice [w*96, w*96+96) ----
    f32x4 acc[6];
    {
        short8 wfrag = *(const short8*)&Wl[l15 * 32 + lh * 8];
#pragma unroll
        for (int i = 0; i < 6; ++i) {
            int d0 = w * 96 + i * 16;
            union { ushort sv[8]; short8 v; } u;
#pragma unroll
            for (int j = 0; j < 8; ++j)
                u.sv[j] = Vl[vidx(lh * 8 + j, d0 + l15)];
            acc[i] = __builtin_amdgcn_mfma_f32_16x16x32_bf16(
                wfrag, u.v, (f32x4){0.f, 0.f, 0.f, 0.f}, 0, 0, 0);
        }
    }

    // ---- epilogue ----
    if (USE_PART) {
        ushort* myp = part + (size_t)(sl * 8 + b) * (TT * DD);
#pragma unroll
        for (int i = 0; i < 6; ++i) {
            ushort4 pk;
            pk.x = f2bf(acc[i][0]); pk.y = f2bf(acc[i][1]);
            pk.z = f2bf(acc[i][2]); pk.w = f2bf(acc[i][3]);
            *(ushort4*)&myp[((w * 6 + i) * 64 + l) * 4] = pk;
        }
    } else {
#pragma unroll
        for (int i = 0; i < 6; ++i) {
            int d0 = w * 96 + i * 16;
#pragma unroll
            for (int q = 0; q < 4; ++q)
                atomicAdd(out + (size_t)(b * TT + lh * 4 + q) * DD + d0 + l15, acc[i][q]);
        }
    }
}

// ---- K1: persistent worker. Ticket loop over 784 tiles; device-scope grid
//      barrier (capacity==grid, co-residency guaranteed by LDS+launch bounds);
//      then in-kernel depth-98 reduce with direct writes. ----
__global__ __launch_bounds__(512, 4) void k_work(const float* __restrict__ x,
                                                 const float* __restrict__ gamma,
                                                 const float* __restrict__ beta,
                                                 const ushort* __restrict__ qn,
                                                 ushort* __restrict__ part,
                                                 float* __restrict__ out,
                                                 int* __restrict__ cnt) {
    __shared__ ushort Vl[32 * DD];      // 49152 B
    __shared__ float  Sl[8 * TT * 33];  // 16896 B
    __shared__ ushort Wl[TT * 32];      // 1024 B
    __shared__ int sTicket;
    int* tk = cnt;
    int* dn = cnt + 1;

    for (;;) {
        if (threadIdx.x == 0) sTicket = atomicAdd(tk, 1);
        __syncthreads();
        int t = sTicket;
        if (t >= NTILE) break;
        tile_body<true>(t, Vl, Sl, Wl, x, gamma, beta, qn, part, out);
        bar_lgkm();                      // Vl/sTicket safe for next iteration
    }

    // ---- grid barrier: release partials, count arrivals, spin till all 512 --
    __threadfence();
    __syncthreads();
    if (threadIdx.x == 0) {
        atomicAdd(dn, 1);
        while (atomicAdd(dn, 0) < NWORK) __builtin_amdgcn_s_sleep(8);
    }
    __syncthreads();
    __threadfence();

    // ---- phase 2: reduce. Block owns 96 ushort2 positions (g in [0,49152)) --
    for (int h = threadIdx.x; h < 96; h += 512) {
        int g = blockIdx.x * 96 + h;
        int b  = g / 6144;
        int hh = g - b * 6144;
        const ushort* src = part + (size_t)b * (TT * DD) + hh * 2;
        float s0 = 0.f, s1 = 0.f;
#pragma unroll 7
        for (int s = 0; s < NSL; ++s) {
            unsigned int u = *(const unsigned int*)(src + (size_t)s * 8 * (TT * DD));
            s0 += bf2f((ushort)(u & 0xffffu));
            s1 += bf2f((ushort)(u >> 16));
        }
        int e     = hh * 2;
        int chunk = e >> 8;            // w*6 + i, 0..47
        int l     = (e >> 2) & 63;
        int q     = e & 3;             // 0 or 2
        int w     = chunk / 6, i = chunk - w * 6;
        int lh    = l >> 4,   l15 = l & 15;
        int d     = w * 96 + i * 16 + l15;
        int tt    = lh * 4 + q;
        float* dst = out + ((size_t)b * TT + tt) * DD + d;
        dst[0]  = s0;
        dst[DD] = s1;
    }
}

// ---- fallback (ws too small): non-persistent, atomic epilogue ----
__global__ __launch_bounds__(512, 4) void k_attn_fb(const float* __restrict__ x,
                                                    const float* __restrict__ gamma,
                                                    const float* __restrict__ beta,
                                                    const ushort* __restrict__ qn,
                                                    float* __restrict__ out) {
    __shared__ ushort Vl[32 * DD];
    __shared__ float  Sl[8 * TT * 33];
    __shared__ ushort Wl[TT * 32];
    tile_body<false>(blockIdx.x, Vl, Sl, Wl, x, gamma, beta, qn, nullptr, out);
}

extern "C" void kernel_launch(void* const* d_in, const int* in_sizes, int n_in,
                              void* d_out, int out_size, void* d_ws, size_t ws_size,
                              hipStream_t stream) {
    const float* x     = (const float*)d_in[0];
    const float* gamma = (const float*)d_in[1];
    const float* beta  = (const float*)d_in[2];
    float* out = (float*)d_out;

    const size_t qn_bytes   = (size_t)NN * DD * 2;                  // 196,608
    const size_t part_bytes = (size_t)NSL * 8 * TT * DD * 2;        // 19,267,584
    ushort* qn   = (ushort*)d_ws;
    ushort* part = (ushort*)((char*)d_ws + qn_bytes);
    int*    cnt  = (int*)((char*)d_ws + qn_bytes + part_bytes);
    bool use_part = ws_size >= qn_bytes + part_bytes + 16;

    k_lnq<<<NN / 4, 256, 0, stream>>>(x, gamma, beta, qn, out, cnt);
    if (use_part) {
        k_work<<<NWORK, 512, 0, stream>>>(x, gamma, beta, qn, part, out, cnt);
    } else {
        k_attn_fb<<<NTILE, 512, 0, stream>>>(x, gamma, beta, qn, out);
    }
}

// Round 21
// 38.695 us; speedup vs baseline: 6.6288x; 6.6288x over previous
//
#include <hip/hip_runtime.h>

#define NN 128
#define DD 768
#define TT 16
#define PP 196
#define NSL 98                    // slices per b, 2 p each
#define SCL 0.03608439182435161f  // 1/sqrt(768)

typedef short short8 __attribute__((ext_vector_type(8)));
typedef short short4v __attribute__((ext_vector_type(4)));
typedef float f32x4 __attribute__((ext_vector_type(4)));

static __device__ __forceinline__ ushort f2bf(float f) {
    union { float f; unsigned int u; } a; a.f = f;
    unsigned int r = a.u + 0x7fffu + ((a.u >> 16) & 1u);
    return (ushort)(r >> 16);
}
static __device__ __forceinline__ float bf2f(ushort u) {
    union { unsigned int u; float f; } c; c.u = (unsigned int)u << 16; return c.f;
}

// Verified (R4/R5/R13) swizzled LDS index for a 32x768 bf16 tile.
static __device__ __forceinline__ int vidx(int r, int d) {
    return r * DD + ((((d >> 3) ^ (r & 7)) << 3) | (d & 7));
}

// Raw workgroup barrier: drain LDS ops only (NOT vmcnt).
static __device__ __forceinline__ void bar_lgkm() {
    asm volatile("s_waitcnt lgkmcnt(0)" ::: "memory");
    __builtin_amdgcn_s_barrier();
    __builtin_amdgcn_sched_barrier(0);
}

// -------- K0: zero out (3 float4/thread) + LayerNorm of 128 cls rows --------
__global__ __launch_bounds__(256) void k_lnq(const float* __restrict__ x,
                                             const float* __restrict__ gamma,
                                             const float* __restrict__ beta,
                                             ushort* __restrict__ qn,
                                             float* __restrict__ out) {
    int zi = blockIdx.x * 256 + threadIdx.x;   // 0..8191
    float4 z = {0.f, 0.f, 0.f, 0.f};
    ((float4*)out)[zi]         = z;
    ((float4*)out)[zi + 8192]  = z;
    ((float4*)out)[zi + 16384] = z;

    int row  = (blockIdx.x << 2) + (threadIdx.x >> 6);   // 0..127
    int lane = threadIdx.x & 63;
    const float4* xr = (const float4*)(x + (size_t)row * DD);
    float4 v[3];
    float s = 0.f, ss = 0.f;
#pragma unroll
    for (int j = 0; j < 3; ++j) {
        v[j] = xr[lane + 64 * j];
        s  += v[j].x + v[j].y + v[j].z + v[j].w;
        ss = fmaf(v[j].x, v[j].x, ss); ss = fmaf(v[j].y, v[j].y, ss);
        ss = fmaf(v[j].z, v[j].z, ss); ss = fmaf(v[j].w, v[j].w, ss);
    }
#pragma unroll
    for (int o = 32; o > 0; o >>= 1) { s += __shfl_xor(s, o); ss += __shfl_xor(ss, o); }
    float mu  = s * (1.f / DD);
    float var = fmaf(ss, 1.f / DD, -mu * mu);
    float rs  = rsqrtf(var + 1e-5f);
    const float4* g4 = (const float4*)gamma;
    const float4* b4 = (const float4*)beta;
    ushort4* outr = (ushort4*)(qn + (size_t)row * DD);
#pragma unroll
    for (int j = 0; j < 3; ++j) {
        int i4 = lane + 64 * j;
        float4 g = g4[i4], b = b4[i4];
        ushort4 o4;
        o4.x = f2bf((v[j].x - mu) * rs * g.x + b.x);
        o4.y = f2bf((v[j].y - mu) * rs * g.y + b.y);
        o4.z = f2bf((v[j].z - mu) * rs * g.z + b.z);
        o4.w = f2bf((v[j].w - mu) * rs * g.w + b.w);
        outr[i4] = o4;
    }
}

// ---- K1: one block per (b, sl), 8 waves, ONE 32-row pass (verbatim R13) ----
template<bool USE_PART>
__global__ __launch_bounds__(512, 4) void k_attn(const float* __restrict__ x,
                                                 const float* __restrict__ gamma,
                                                 const float* __restrict__ beta,
                                                 const ushort* __restrict__ qn,
                                                 ushort* __restrict__ part,
                                                 float* __restrict__ out) {
    __shared__ ushort Vl[32 * DD];      // 49152 B, swizzled
    __shared__ float  Sl[8][TT][33];    // 16896 B
    __shared__ ushort Wl[TT][32];       // 1024 B

    int gid = blockIdx.x;
    int b = gid & 7, sl = gid >> 3;     // sl = 0..97
    int w = threadIdx.x >> 6, l = threadIdx.x & 63;
    int l15 = l & 15, lh = l >> 4;

    // ---- stage: thread = (row r = tid>>4, j = tid&15); LN fused, pack bf16 --
    {
        int r = threadIdx.x >> 4, j = threadIdx.x & 15;
        const float* vrow =
            x + ((size_t)(1 + sl * 2 + (r >> 4)) * NN + b * TT + (r & 15)) * DD;
        float4 c[12];
#pragma unroll
        for (int k = 0; k < 12; ++k) c[k] = *(const float4*)(vrow + (j + 16 * k) * 4);
        float s1 = 0.f, s2 = 0.f;
#pragma unroll
        for (int k = 0; k < 12; ++k) {
            float4 v = c[k];
            s1 += v.x + v.y + v.z + v.w;
            s2 = fmaf(v.x, v.x, s2); s2 = fmaf(v.y, v.y, s2);
            s2 = fmaf(v.z, v.z, s2); s2 = fmaf(v.w, v.w, s2);
        }
#pragma unroll
        for (int o = 1; o < 16; o <<= 1) { s1 += __shfl_xor(s1, o); s2 += __shfl_xor(s2, o); }
        float mu  = s1 * (1.f / DD);
        float var = fmaf(s2, 1.f / DD, -mu * mu);
        float rs  = rsqrtf(var + 1e-5f);
        const float4* g4 = (const float4*)gamma;
        const float4* b4 = (const float4*)beta;
#pragma unroll
        for (int k = 0; k < 12; ++k) {
            int c4 = j + 16 * k;
            float4 g = g4[c4], e = b4[c4];
            float4 v = c[k];
            ushort4 ut;
            ut.x = f2bf((v.x - mu) * rs * g.x + e.x);
            ut.y = f2bf((v.y - mu) * rs * g.y + e.y);
            ut.z = f2bf((v.z - mu) * rs * g.z + e.z);
            ut.w = f2bf((v.w - mu) * rs * g.w + e.w);
            *(ushort4*)&Vl[vidx(r, c4 * 4)] = ut;
        }
    }
    bar_lgkm();

    // ---- mm1: wave w covers K-slice [w*96, w*96+96), both 16-col groups ----
    {
        const ushort* qrow = qn + (size_t)(b * TT + l15) * DD + w * 96 + lh * 8;
        short8 qf[3];
#pragma unroll
        for (int s = 0; s < 3; ++s) qf[s] = *(const short8*)(qrow + s * 32);
#pragma unroll
        for (int cg = 0; cg < 2; ++cg) {
            f32x4 sacc = (f32x4){0.f, 0.f, 0.f, 0.f};
            int vr = cg * 16 + l15;
#pragma unroll
            for (int s = 0; s < 3; ++s) {
                int k0 = w * 96 + s * 32 + lh * 8;
                short8 bfr = *(const short8*)&Vl[vidx(vr, k0)];
                sacc = __builtin_amdgcn_mfma_f32_16x16x32_bf16(qf[s], bfr, sacc, 0, 0, 0);
            }
#pragma unroll
            for (int q = 0; q < 4; ++q) Sl[w][lh * 4 + q][cg * 16 + l15] = sacc[q];
        }
    }
    bar_lgkm();

    // ---- W: 512 threads = (t, rr in 0..31): sum 8 K-slices, band sigmoid ----
    {
        int t  = threadIdx.x >> 5, rr = threadIdx.x & 31;
        float s = 0.f;
#pragma unroll
        for (int k = 0; k < 8; ++k) s += Sl[k][t][rr];
        int m = rr & 15;
        int dlt = m - t;
        float wv = (dlt <= 2 && dlt >= -2)
                     ? (1.f / (1.f + __expf(-s * SCL)) - 0.5f) : 0.f;
        Wl[t][rr] = f2bf(wv);
    }
    bar_lgkm();

    // ---- mm2: K=32 (all real rows), wave owns d-slice [w*96, w*96+96) ----
    f32x4 acc[6];
    {
        short8 wfrag = *(const short8*)&Wl[l15][lh * 8];
#pragma unroll
        for (int i = 0; i < 6; ++i) {
            int d0 = w * 96 + i * 16;
            union { ushort sv[8]; short8 v; } u;
#pragma unroll
            for (int j = 0; j < 8; ++j)
                u.sv[j] = Vl[vidx(lh * 8 + j, d0 + l15)];
            acc[i] = __builtin_amdgcn_mfma_f32_16x16x32_bf16(
                wfrag, u.v, (f32x4){0.f, 0.f, 0.f, 0.f}, 0, 0, 0);
        }
    }

    // ---- epilogue: fragment-order coalesced partial store ----
    if (USE_PART) {
        ushort* myp = part + (size_t)(sl * 8 + b) * (TT * DD);
#pragma unroll
        for (int i = 0; i < 6; ++i) {
            ushort4 pk;
            pk.x = f2bf(acc[i][0]); pk.y = f2bf(acc[i][1]);
            pk.z = f2bf(acc[i][2]); pk.w = f2bf(acc[i][3]);
            *(ushort4*)&myp[((w * 6 + i) * 64 + l) * 4] = pk;
        }
    } else {
#pragma unroll
        for (int i = 0; i < 6; ++i) {
            int d0 = w * 96 + i * 16;
#pragma unroll
            for (int q = 0; q < 4; ++q)
                atomicAdd(out + (size_t)(b * TT + lh * 4 + q) * DD + d0 + l15, acc[i][q]);
        }
    }
}

// ---- K2: reduce 98 fragment-order bf16 partials; 7 slice-chunks x 96 blocks -
__global__ __launch_bounds__(256) void k_reduce(const ushort* __restrict__ part,
                                                float* __restrict__ out) {
    int bid = blockIdx.x;
    int pc  = bid % 7;                       // slice-chunk: 14 slices
    int g   = (bid / 7) * 256 + threadIdx.x; // 0..24575: (b, pos4)
    int b    = g / 3072;
    int pos4 = g - b * 3072;                 // float4-group within slice
    const ushort* src = part + (size_t)b * (TT * DD) + pos4 * 4;

    float s0 = 0.f, s1 = 0.f, s2 = 0.f, s3 = 0.f;
#pragma unroll 2
    for (int s = pc * 14; s < pc * 14 + 14; ++s) {
        union { short4v v; ushort sv[4]; } u;
        u.v = *(const short4v*)(src + (size_t)s * 8 * (TT * DD));
        s0 += bf2f(u.sv[0]); s1 += bf2f(u.sv[1]);
        s2 += bf2f(u.sv[2]); s3 += bf2f(u.sv[3]);
    }
    // decode fragment position -> (t, d): chunk = w*6+i
    int fp    = pos4 * 4;
    int chunk = fp >> 8;           // 0..47
    int l     = (fp >> 2) & 63;
    int w     = chunk / 6, i = chunk - w * 6;
    int lh    = l >> 4,   l15 = l & 15;
    int d     = w * 96 + i * 16 + l15;
    float* dst = out + ((size_t)b * TT + lh * 4) * DD + d;
    atomicAdd(dst,          s0);
    atomicAdd(dst + 1 * DD, s1);
    atomicAdd(dst + 2 * DD, s2);
    atomicAdd(dst + 3 * DD, s3);
}

extern "C" void kernel_launch(void* const* d_in, const int* in_sizes, int n_in,
                              void* d_out, int out_size, void* d_ws, size_t ws_size,
                              hipStream_t stream) {
    const float* x     = (const float*)d_in[0];
    const float* gamma = (const float*)d_in[1];
    const float* beta  = (const float*)d_in[2];
    float* out = (float*)d_out;

    const size_t qn_bytes   = (size_t)NN * DD * 2;                  // 196,608
    const size_t part_bytes = (size_t)NSL * 8 * TT * DD * 2;        // 19,267,584
    ushort* qn   = (ushort*)d_ws;
    ushort* part = (ushort*)((char*)d_ws + qn_bytes);
    bool use_part = ws_size >= qn_bytes + part_bytes;

    k_lnq<<<NN / 4, 256, 0, stream>>>(x, gamma, beta, qn, out);
    if (use_part) {
        k_attn<true><<<8 * NSL, 512, 0, stream>>>(x, gamma, beta, qn, part, out);
        k_reduce<<<7 * 96, 256, 0, stream>>>(part, out);
    } else {
        k_attn<false><<<8 * NSL, 512, 0, stream>>>(x, gamma, beta, qn, part, out);
    }
}